// Round 1
// baseline (4235.656 us; speedup 1.0000x reference)
//
#include <hip/hip_runtime.h>
#include <math.h>

#define LN_EPS 1e-5f
#define BN_EPS 1e-5f

// ============================================================================
// Shapes: B=1, N=4 views, DIM=FDIM=128, BEV H=W=256, feat FH=FW=32,
// query window 16x16, feature window 2x2, HEADS=4, DH=32.
// ============================================================================

// ---------------- kernel 1: img_embed (n,128,32,32) -------------------------
__global__ void k_img_embed(const float* __restrict__ I_inv,
                            const float* __restrict__ E_inv,
                            const float* __restrict__ img_w,
                            const float* __restrict__ cam_w,
                            float* __restrict__ img_embed)
{
    const int blk = blockIdx.x;          // n*1024 + p, p = fy*32+fx
    const int n = blk >> 10, p = blk & 1023;
    const int fy = p >> 5, fx = p & 31;
    const float px = fx * (256.0f / 31.0f);   // linspace(0,1,32)*256
    const float py = fy * (256.0f / 31.0f);
    const float* Iv = I_inv + n * 9;
    const float* Ev = E_inv + n * 16;
    const float c0 = Iv[0]*px + Iv[1]*py + Iv[2];
    const float c1 = Iv[3]*px + Iv[4]*py + Iv[5];
    const float c2 = Iv[6]*px + Iv[7]*py + Iv[8];
    const float d0 = Ev[0]*c0 + Ev[1]*c1 + Ev[2]*c2 + Ev[3];
    const float d1 = Ev[4]*c0 + Ev[5]*c1 + Ev[6]*c2 + Ev[7];
    const float d2 = Ev[8]*c0 + Ev[9]*c1 + Ev[10]*c2 + Ev[11];
    const float d3 = Ev[12]*c0 + Ev[13]*c1 + Ev[14]*c2 + Ev[15];
    const int c = threadIdx.x;
    const float ce = cam_w[c*4+0]*Ev[3] + cam_w[c*4+1]*Ev[7]
                   + cam_w[c*4+2]*Ev[11] + cam_w[c*4+3]*Ev[15];
    float v = img_w[c*4+0]*d0 + img_w[c*4+1]*d1
            + img_w[c*4+2]*d2 + img_w[c*4+3]*d3 - ce;
    __shared__ float red[128];
    red[c] = v * v;
    __syncthreads();
    for (int s = 64; s > 0; s >>= 1) {
        if (c < s) red[c] += red[c + s];
        __syncthreads();
    }
    img_embed[(n*128 + c)*1024 + p] = v / (sqrtf(red[0]) + 1e-7f);
}

// ---------------- kernel 2: key/val = BN+ReLU+1x1conv (+img_embed) ----------
__global__ void k_keyval(const float* __restrict__ feature,
                         const float* __restrict__ img_embed,
                         const float* __restrict__ fp_g, const float* __restrict__ fp_b,
                         const float* __restrict__ fp_m, const float* __restrict__ fp_v,
                         const float* __restrict__ fp_w,
                         const float* __restrict__ fl_g, const float* __restrict__ fl_b,
                         const float* __restrict__ fl_m, const float* __restrict__ fl_v,
                         const float* __restrict__ fl_w,
                         float* __restrict__ key, float* __restrict__ val)
{
    const int blk = blockIdx.x;          // n*1024 + p
    const int n = blk >> 10, p = blk & 1023;
    const int c = threadIdx.x;
    __shared__ float sp[128], sl[128];
    const float f = feature[(n*128 + c)*1024 + p];
    const float xp = (f - fp_m[c]) * rsqrtf(fp_v[c] + BN_EPS) * fp_g[c] + fp_b[c];
    const float xl = (f - fl_m[c]) * rsqrtf(fl_v[c] + BN_EPS) * fl_g[c] + fl_b[c];
    sp[c] = fmaxf(xp, 0.f);
    sl[c] = fmaxf(xl, 0.f);
    __syncthreads();
    float ak = 0.f, av = 0.f;
    const float* wkr = fp_w + c*128;
    const float* wvr = fl_w + c*128;
    for (int i = 0; i < 128; i++) { ak += wkr[i]*sp[i]; av += wvr[i]*sl[i]; }
    key[(n*128 + c)*1024 + p] = img_embed[(n*128 + c)*1024 + p] + ak;
    val[(n*128 + c)*1024 + p] = av;
}

// ---------------- kernel 3: k/v LN + projections for BOTH stages ------------
// One LN normalization of key (and val), then 4 affine+proj outputs.
// Output layout: (n, fh, fw, 128) -> token-contiguous for attention gathers.
__global__ void k_kvproj(const float* __restrict__ key, const float* __restrict__ val,
                         const float* __restrict__ k1g, const float* __restrict__ k1b,
                         const float* __restrict__ wk1, const float* __restrict__ bk1,
                         const float* __restrict__ v1g, const float* __restrict__ v1b,
                         const float* __restrict__ wv1, const float* __restrict__ bv1,
                         const float* __restrict__ k2g, const float* __restrict__ k2b,
                         const float* __restrict__ wk2, const float* __restrict__ bk2,
                         const float* __restrict__ v2g, const float* __restrict__ v2b,
                         const float* __restrict__ wv2, const float* __restrict__ bv2,
                         float* __restrict__ kp1, float* __restrict__ vp1,
                         float* __restrict__ kp2, float* __restrict__ vp2)
{
    const int blk = blockIdx.x;          // n*1024 + p
    const int n = blk >> 10, p = blk & 1023;
    const int c = threadIdx.x;
    __shared__ float a1[128], a2[128], a3[128], a4[128];
    __shared__ float red[128], red2[128];

    const float kv = key[(n*128 + c)*1024 + p];
    red[c] = kv; red2[c] = kv*kv;
    __syncthreads();
    for (int s = 64; s > 0; s >>= 1) {
        if (c < s) { red[c] += red[c+s]; red2[c] += red2[c+s]; }
        __syncthreads();
    }
    const float kmean = red[0]*(1.f/128.f);
    const float kvar  = red2[0]*(1.f/128.f) - kmean*kmean;
    const float khat  = (kv - kmean) * rsqrtf(kvar + LN_EPS);
    __syncthreads();

    const float vv = val[(n*128 + c)*1024 + p];
    red[c] = vv; red2[c] = vv*vv;
    __syncthreads();
    for (int s = 64; s > 0; s >>= 1) {
        if (c < s) { red[c] += red[c+s]; red2[c] += red2[c+s]; }
        __syncthreads();
    }
    const float vmean = red[0]*(1.f/128.f);
    const float vvar  = red2[0]*(1.f/128.f) - vmean*vmean;
    const float vhat  = (vv - vmean) * rsqrtf(vvar + LN_EPS);
    __syncthreads();

    a1[c] = khat*k1g[c] + k1b[c];
    a2[c] = vhat*v1g[c] + v1b[c];
    a3[c] = khat*k2g[c] + k2b[c];
    a4[c] = vhat*v2g[c] + v2b[c];
    __syncthreads();

    float s1 = bk1[c], s2 = bv1[c], s3 = bk2[c], s4 = bv2[c];
    const float* r1 = wk1 + c*128;
    const float* r2 = wv1 + c*128;
    const float* r3 = wk2 + c*128;
    const float* r4 = wv2 + c*128;
    for (int i = 0; i < 128; i++) {
        s1 += r1[i]*a1[i];
        s2 += r2[i]*a2[i];
        s3 += r3[i]*a3[i];
        s4 += r4[i]*a4[i];
    }
    const int o = (n*1024 + p)*128 + c;
    kp1[o] = s1; vp1[o] = s2; kp2[o] = s3; vp2[o] = s4;
}

// ---------------- kernel 4: stage-1 window cross-attention ------------------
// Block = 256 threads = 64 q-positions (4 rows of a 16x16 window) x 4 parts.
// Loops over n=4 views; query (bev-embed + x) generated on the fly;
// out-proj accumulated in registers (mean over views = 0.25x).
__global__ __launch_bounds__(256) void k_attn1(
    const float* __restrict__ x,
    const float* __restrict__ kp, const float* __restrict__ vp,
    const float* __restrict__ E_inv,
    const float* __restrict__ bev_w, const float* __restrict__ bev_b,
    const float* __restrict__ cam_w,
    const float* __restrict__ nqg, const float* __restrict__ nqb,
    const float* __restrict__ wq, const float* __restrict__ bq,
    const float* __restrict__ wp, const float* __restrict__ bp,
    float* __restrict__ z1)
{
    __shared__ float kbuf[16][128];
    __shared__ float vbuf[16][128];
    __shared__ float qa[64][129];     // q_ln, then att output (time-shared)

    const int blk = blockIdx.x;       // win*4 + rowgroup
    const int win = blk >> 2, rg = blk & 3;
    const int wx = win >> 4, wy = win & 15;
    const int tid = threadIdx.x;

    // gather k/v proj for this window: token j = nk*4 + f1*2 + f2 (local part.)
    for (int idx = tid; idx < 16*128; idx += 256) {
        int j = idx >> 7, c = idx & 127;
        int nk = j >> 2, f1 = (j >> 1) & 1, f2 = j & 1;
        int src = (nk*1024 + (wx*2+f1)*32 + (wy*2+f2))*128 + c;
        kbuf[j][c] = kp[src];
        vbuf[j][c] = vp[src];
    }

    const int t = tid >> 2, part = tid & 3;     // token in [0,64), channel part
    const int w1 = rg*4 + (t >> 4), w2 = t & 15;
    const int h = wx*16 + w1, w = wy*16 + w2;
    // world coords (inv(Vm) applied to the bev grid)
    const float world0 = 50.f - (float)h * (100.f/255.f);
    const float world1 = 50.f - (float)w * (100.f/255.f);

    float base[32], xv[32];
#pragma unroll
    for (int k = 0; k < 32; k++) {
        int c = part*32 + k;
        base[k] = bev_w[c*2+0]*world0 + bev_w[c*2+1]*world1 + bev_b[c];
        xv[k]   = x[c*65536 + h*256 + w];
    }

    const int o = tid & 127, grp = tid >> 7;    // out-proj mapping
    float oreg[32];
#pragma unroll
    for (int k = 0; k < 32; k++) oreg[k] = 0.f;

    for (int n = 0; n < 4; n++) {
        const float* Ev = E_inv + n*16;
        // ---- phase a: query gen (normalize bev embed, +x) then LayerNorm ----
        float r[32]; float ss = 0.f;
#pragma unroll
        for (int k = 0; k < 32; k++) {
            int c = part*32 + k;
            float ce = cam_w[c*4+0]*Ev[3] + cam_w[c*4+1]*Ev[7]
                     + cam_w[c*4+2]*Ev[11] + cam_w[c*4+3]*Ev[15];
            float e = base[k] - ce;
            r[k] = e; ss += e*e;
        }
        ss += __shfl_xor(ss, 1); ss += __shfl_xor(ss, 2);
        const float invn = 1.f / (sqrtf(ss) + 1e-7f);
        float s1 = 0.f, s2 = 0.f;
#pragma unroll
        for (int k = 0; k < 32; k++) {
            float qv = r[k]*invn + xv[k];
            r[k] = qv; s1 += qv; s2 += qv*qv;
        }
        s1 += __shfl_xor(s1, 1); s1 += __shfl_xor(s1, 2);
        s2 += __shfl_xor(s2, 1); s2 += __shfl_xor(s2, 2);
        const float mean = s1*(1.f/128.f);
        const float var  = s2*(1.f/128.f) - mean*mean;
        const float rstd = rsqrtf(var + LN_EPS);
#pragma unroll
        for (int k = 0; k < 32; k++) {
            int c = part*32 + k;
            qa[t][c] = (r[k]-mean)*rstd*nqg[c] + nqb[c];
        }
        __syncthreads();

        // ---- phase b1: q projection for (token t, head hd=part) ----
        const int hd = part;
        float qp[32];
#pragma unroll
        for (int d = 0; d < 32; d++) qp[d] = bq[hd*32 + d];
        for (int i = 0; i < 128; i++) {
            float qv = qa[t][i];
            const float* wcol = wq + (hd*32)*128 + i;
#pragma unroll
            for (int d = 0; d < 32; d++) qp[d] += wcol[d*128] * qv;
        }
        __syncthreads();

        // ---- phase b2: scores, softmax over 16 keys, PV; att -> qa ----
        float sc[16]; float mx = -1e30f;
#pragma unroll
        for (int j = 0; j < 16; j++) {
            float a = 0.f;
#pragma unroll
            for (int d = 0; d < 32; d++) a += qp[d]*kbuf[j][hd*32+d];
            a *= 0.1767766953f;       // 32^-0.5
            sc[j] = a; mx = fmaxf(mx, a);
        }
        float sum = 0.f;
#pragma unroll
        for (int j = 0; j < 16; j++) { sc[j] = expf(sc[j]-mx); sum += sc[j]; }
        const float isum = 1.f/sum;
#pragma unroll
        for (int d = 0; d < 32; d++) {
            float ov = 0.f;
#pragma unroll
            for (int j = 0; j < 16; j++) ov += sc[j]*vbuf[j][hd*32+d];
            qa[t][hd*32+d] = ov*isum;
        }
        __syncthreads();

        // ---- phase c: out projection, accumulate 0.25x into registers ----
        const float* wr = wp + o*128;
        float pa[32];
#pragma unroll
        for (int k = 0; k < 32; k++) pa[k] = 0.f;
        for (int i = 0; i < 128; i++) {
            float wv = wr[i];
#pragma unroll
            for (int k = 0; k < 32; k++) pa[k] += wv * qa[grp*32+k][i];
        }
        const float bb = bp[o];
#pragma unroll
        for (int k = 0; k < 32; k++) oreg[k] += 0.25f*(pa[k] + bb);
        __syncthreads();
    }

    // epilogue: + skip(x), write z1 (H,W,128)
#pragma unroll
    for (int k = 0; k < 32; k++) {
        int tt = grp*32 + k;
        int he = wx*16 + rg*4 + (tt >> 4), we = wy*16 + (tt & 15);
        z1[(he*256+we)*128 + o] = oreg[k] + x[o*65536 + he*256 + we];
    }
}

// ---------------- kernel 5/7: residual MLP (LN -> 256 gelu -> 128) ----------
__global__ __launch_bounds__(256) void k_mlp(
    float* __restrict__ z,
    const float* __restrict__ g, const float* __restrict__ bta,
    const float* __restrict__ w1, const float* __restrict__ b1,
    const float* __restrict__ w2, const float* __restrict__ b2)
{
    __shared__ float ln[16][129];
    __shared__ float hid[16][257];
    const int base = blockIdx.x * 16;          // 16 tokens per block
    const int tid = threadIdx.x;
    const int tk = tid >> 4, part = tid & 15;  // 16 threads per token

    const float* zr = z + (base + tk)*128;
    float r[8]; float s1 = 0.f, s2 = 0.f;
#pragma unroll
    for (int k = 0; k < 8; k++) { float v = zr[part*8+k]; r[k] = v; s1 += v; s2 += v*v; }
#pragma unroll
    for (int d = 1; d < 16; d <<= 1) { s1 += __shfl_xor(s1, d); s2 += __shfl_xor(s2, d); }
    const float mean = s1*(1.f/128.f);
    const float var  = s2*(1.f/128.f) - mean*mean;
    const float rstd = rsqrtf(var + LN_EPS);
#pragma unroll
    for (int k = 0; k < 8; k++) {
        int c = part*8 + k;
        ln[tk][c] = (r[k]-mean)*rstd*g[c] + bta[c];
    }
    __syncthreads();

    // hidden: each thread = one of 256 hidden units, all 16 tokens
    {
        float acc[16];
#pragma unroll
        for (int t = 0; t < 16; t++) acc[t] = 0.f;
        const float* wr = w1 + tid*128;
        for (int d = 0; d < 128; d++) {
            float wv = wr[d];
#pragma unroll
            for (int t = 0; t < 16; t++) acc[t] += wv * ln[t][d];
        }
        const float bb = b1[tid];
#pragma unroll
        for (int t = 0; t < 16; t++) {
            float hv = acc[t] + bb;
            hid[t][tid] = 0.5f*hv*(1.f + erff(hv*0.70710678118f));  // exact gelu
        }
    }
    __syncthreads();

    // out: threads 0..127 = out channel, all 16 tokens, residual add in-place
    if (tid < 128) {
        float acc[16];
#pragma unroll
        for (int t = 0; t < 16; t++) acc[t] = 0.f;
        const float* wr = w2 + tid*256;
        for (int kk = 0; kk < 256; kk++) {
            float wv = wr[kk];
#pragma unroll
            for (int t = 0; t < 16; t++) acc[t] += wv * hid[t][kk];
        }
        const float bb = b2[tid];
#pragma unroll
        for (int t = 0; t < 16; t++) {
            int oidx = (base + t)*128 + tid;
            z[oidx] = z[oidx] + acc[t] + bb;
        }
    }
}

// ---------------- kernel 6: stage-2 attention (views collapse) --------------
// q is broadcast over views and keys are the combined 16-token set, so the
// per-view outputs are identical and mean(3) is a no-op: single pass.
__global__ __launch_bounds__(256) void k_attn2(
    const float* __restrict__ z1,
    const float* __restrict__ kp, const float* __restrict__ vp,
    const float* __restrict__ nqg, const float* __restrict__ nqb,
    const float* __restrict__ wq, const float* __restrict__ bq,
    const float* __restrict__ wp, const float* __restrict__ bp,
    float* __restrict__ z2)
{
    __shared__ float kbuf[16][128];
    __shared__ float vbuf[16][128];
    __shared__ float qa[64][129];

    const int blk = blockIdx.x;
    const int win = blk >> 2, rg = blk & 3;
    const int wx = win >> 4, wy = win & 15;
    const int tid = threadIdx.x;

    // gather k/v proj: GRID partition: fh = f1*16 + wx, fw = f2*16 + wy
    for (int idx = tid; idx < 16*128; idx += 256) {
        int j = idx >> 7, c = idx & 127;
        int nk = j >> 2, f1 = (j >> 1) & 1, f2 = j & 1;
        int src = (nk*1024 + (f1*16+wx)*32 + (f2*16+wy))*128 + c;
        kbuf[j][c] = kp[src];
        vbuf[j][c] = vp[src];
    }

    const int t = tid >> 2, part = tid & 3;
    const int w1 = rg*4 + (t >> 4), w2 = t & 15;
    const int h = wx*16 + w1, w = wy*16 + w2;
    const float* zr = z1 + (h*256+w)*128;
    float r[32]; float s1 = 0.f, s2 = 0.f;
#pragma unroll
    for (int k = 0; k < 32; k++) { float v = zr[part*32+k]; r[k] = v; s1 += v; s2 += v*v; }
    s1 += __shfl_xor(s1, 1); s1 += __shfl_xor(s1, 2);
    s2 += __shfl_xor(s2, 1); s2 += __shfl_xor(s2, 2);
    const float mean = s1*(1.f/128.f);
    const float var  = s2*(1.f/128.f) - mean*mean;
    const float rstd = rsqrtf(var + LN_EPS);
#pragma unroll
    for (int k = 0; k < 32; k++) {
        int c = part*32 + k;
        qa[t][c] = (r[k]-mean)*rstd*nqg[c] + nqb[c];
    }
    __syncthreads();

    const int hd = part;
    float qp[32];
#pragma unroll
    for (int d = 0; d < 32; d++) qp[d] = bq[hd*32 + d];
    for (int i = 0; i < 128; i++) {
        float qv = qa[t][i];
        const float* wcol = wq + (hd*32)*128 + i;
#pragma unroll
        for (int d = 0; d < 32; d++) qp[d] += wcol[d*128] * qv;
    }
    __syncthreads();

    float sc[16]; float mx = -1e30f;
#pragma unroll
    for (int j = 0; j < 16; j++) {
        float a = 0.f;
#pragma unroll
        for (int d = 0; d < 32; d++) a += qp[d]*kbuf[j][hd*32+d];
        a *= 0.1767766953f;
        sc[j] = a; mx = fmaxf(mx, a);
    }
    float sum = 0.f;
#pragma unroll
    for (int j = 0; j < 16; j++) { sc[j] = expf(sc[j]-mx); sum += sc[j]; }
    const float isum = 1.f/sum;
#pragma unroll
    for (int d = 0; d < 32; d++) {
        float ov = 0.f;
#pragma unroll
        for (int j = 0; j < 16; j++) ov += sc[j]*vbuf[j][hd*32+d];
        qa[t][hd*32+d] = ov*isum;
    }
    __syncthreads();

    const int o = tid & 127, grp = tid >> 7;
    const float* wr = wp + o*128;
    float pa[32];
#pragma unroll
    for (int k = 0; k < 32; k++) pa[k] = 0.f;
    for (int i = 0; i < 128; i++) {
        float wv = wr[i];
#pragma unroll
        for (int k = 0; k < 32; k++) pa[k] += wv * qa[grp*32+k][i];
    }
    const float bb = bp[o];
#pragma unroll
    for (int k = 0; k < 32; k++) {
        int tt = grp*32 + k;
        int he = wx*16 + rg*4 + (tt >> 4), we = wy*16 + (tt & 15);
        int gi = (he*256+we)*128 + o;
        z2[gi] = pa[k] + bb + z1[gi];   // + skip (z1 itself)
    }
}

// ---------------- kernel 8: final LN + transpose to (128,256,256) -----------
__global__ __launch_bounds__(256) void k_post(
    const float* __restrict__ z2,
    const float* __restrict__ g, const float* __restrict__ b,
    float* __restrict__ out)
{
    __shared__ float buf[64][129];
    const int blk = blockIdx.x;           // h*4 + quarter
    const int h = blk >> 2, w0 = (blk & 3)*64;
    const int tid = threadIdx.x;
    const int t = tid >> 2, part = tid & 3;

    const float* zr = z2 + (h*256 + w0 + t)*128;
    float r[32]; float s1 = 0.f, s2 = 0.f;
#pragma unroll
    for (int k = 0; k < 32; k++) { float v = zr[part*32+k]; r[k] = v; s1 += v; s2 += v*v; }
    s1 += __shfl_xor(s1, 1); s1 += __shfl_xor(s1, 2);
    s2 += __shfl_xor(s2, 1); s2 += __shfl_xor(s2, 2);
    const float mean = s1*(1.f/128.f);
    const float var  = s2*(1.f/128.f) - mean*mean;
    const float rstd = rsqrtf(var + LN_EPS);
#pragma unroll
    for (int k = 0; k < 32; k++) {
        int c = part*32 + k;
        buf[t][c] = (r[k]-mean)*rstd*g[c] + b[c];
    }
    __syncthreads();
    for (int idx = tid; idx < 64*128; idx += 256) {
        int c = idx >> 6, wl = idx & 63;
        out[(c*256 + h)*256 + w0 + wl] = buf[wl][c];
    }
}

// ============================================================================
extern "C" void kernel_launch(void* const* d_in, const int* in_sizes, int n_in,
                              void* d_out, int out_size, void* d_ws, size_t ws_size,
                              hipStream_t stream)
{
    (void)in_sizes; (void)n_in; (void)out_size; (void)ws_size;
    const float* x       = (const float*)d_in[1];
    const float* feature = (const float*)d_in[2];
    const float* I_inv   = (const float*)d_in[3];
    const float* E_inv   = (const float*)d_in[4];
    const float* fl_g = (const float*)d_in[5],  *fl_b = (const float*)d_in[6];
    const float* fl_m = (const float*)d_in[7],  *fl_v = (const float*)d_in[8];
    const float* fl_w = (const float*)d_in[9];
    const float* fp_g = (const float*)d_in[10], *fp_b = (const float*)d_in[11];
    const float* fp_m = (const float*)d_in[12], *fp_v = (const float*)d_in[13];
    const float* fp_w = (const float*)d_in[14];
    const float* bev_w = (const float*)d_in[15], *bev_b = (const float*)d_in[16];
    const float* img_w = (const float*)d_in[17], *cam_w = (const float*)d_in[18];
    const float* a1_nq_g = (const float*)d_in[19], *a1_nq_b = (const float*)d_in[20];
    const float* a1_wq = (const float*)d_in[21], *a1_bq = (const float*)d_in[22];
    const float* a1_nk_g = (const float*)d_in[23], *a1_nk_b = (const float*)d_in[24];
    const float* a1_wk = (const float*)d_in[25], *a1_bk = (const float*)d_in[26];
    const float* a1_nv_g = (const float*)d_in[27], *a1_nv_b = (const float*)d_in[28];
    const float* a1_wv = (const float*)d_in[29], *a1_bv = (const float*)d_in[30];
    const float* a1_wp = (const float*)d_in[31], *a1_bp = (const float*)d_in[32];
    const float* pn1_g = (const float*)d_in[33], *pn1_b = (const float*)d_in[34];
    const float* m1_w1 = (const float*)d_in[35], *m1_b1 = (const float*)d_in[36];
    const float* m1_w2 = (const float*)d_in[37], *m1_b2 = (const float*)d_in[38];
    const float* a2_nq_g = (const float*)d_in[39], *a2_nq_b = (const float*)d_in[40];
    const float* a2_wq = (const float*)d_in[41], *a2_bq = (const float*)d_in[42];
    const float* a2_nk_g = (const float*)d_in[43], *a2_nk_b = (const float*)d_in[44];
    const float* a2_wk = (const float*)d_in[45], *a2_bk = (const float*)d_in[46];
    const float* a2_nv_g = (const float*)d_in[47], *a2_nv_b = (const float*)d_in[48];
    const float* a2_wv = (const float*)d_in[49], *a2_bv = (const float*)d_in[50];
    const float* a2_wp = (const float*)d_in[51], *a2_bp = (const float*)d_in[52];
    const float* pn2_g = (const float*)d_in[53], *pn2_b = (const float*)d_in[54];
    const float* m2_w1 = (const float*)d_in[55], *m2_b1 = (const float*)d_in[56];
    const float* m2_w2 = (const float*)d_in[57], *m2_b2 = (const float*)d_in[58];
    const float* post_g = (const float*)d_in[59], *post_b = (const float*)d_in[60];

    float* ws  = (float*)d_ws;
    float* img = ws;                       // 4*128*1024 = 524288 floats each
    float* key = ws + 524288;
    float* val = ws + 1048576;
    float* kp1 = ws + 1572864;
    float* vp1 = ws + 2097152;
    float* kp2 = ws + 2621440;
    float* vp2 = ws + 3145728;
    float* z2  = ws + 3670016;             // 256*256*128 floats
    float* z1  = (float*)d_out;            // stage-1 output lives in d_out

    k_img_embed<<<4096, 128, 0, stream>>>(I_inv, E_inv, img_w, cam_w, img);
    k_keyval<<<4096, 128, 0, stream>>>(feature, img,
                                       fp_g, fp_b, fp_m, fp_v, fp_w,
                                       fl_g, fl_b, fl_m, fl_v, fl_w,
                                       key, val);
    k_kvproj<<<4096, 128, 0, stream>>>(key, val,
                                       a1_nk_g, a1_nk_b, a1_wk, a1_bk,
                                       a1_nv_g, a1_nv_b, a1_wv, a1_bv,
                                       a2_nk_g, a2_nk_b, a2_wk, a2_bk,
                                       a2_nv_g, a2_nv_b, a2_wv, a2_bv,
                                       kp1, vp1, kp2, vp2);
    k_attn1<<<1024, 256, 0, stream>>>(x, kp1, vp1, E_inv, bev_w, bev_b, cam_w,
                                      a1_nq_g, a1_nq_b, a1_wq, a1_bq,
                                      a1_wp, a1_bp, z1);
    k_mlp<<<4096, 256, 0, stream>>>(z1, pn1_g, pn1_b, m1_w1, m1_b1, m1_w2, m1_b2);
    k_attn2<<<1024, 256, 0, stream>>>(z1, kp2, vp2,
                                      a2_nq_g, a2_nq_b, a2_wq, a2_bq,
                                      a2_wp, a2_bp, z2);
    k_mlp<<<4096, 256, 0, stream>>>(z2, pn2_g, pn2_b, m2_w1, m2_b1, m2_w2, m2_b2);
    k_post<<<1024, 256, 0, stream>>>(z2, post_g, post_b, (float*)d_out);
}